// Round 2
// baseline (9928.779 us; speedup 1.0000x reference)
//
#include <hip/hip_runtime.h>
#include <hip/hip_bf16.h>

typedef __hip_bfloat16 bf16;

__device__ __forceinline__ float b2f(bf16 v){ return __bfloat162float(v); }
__device__ __forceinline__ bf16  f2b(float v){ return __float2bfloat16(v); }

#define EPSV 1e-5f

// ===== weight transpose: OIHW (OC,CI,3,3) f32 -> [k9][CI][OC] bf16, OC=512 =
__global__ __launch_bounds__(256) void k_wt(const float* __restrict__ w,
                                            bf16* __restrict__ wt, int CI) {
  int oc0 = blockIdx.x * 32, ci0 = blockIdx.y * 8;
  for (int i = threadIdx.x; i < 2304; i += 256) {
    int kk = i >> 8, r = i & 255;
    int ci = ci0 + (r >> 5), oc = oc0 + (r & 31);
    wt[((size_t)kk * CI + ci) * 512 + oc] = f2b(w[((size_t)oc * CI + ci) * 9 + kk]);
  }
}

// ===== F (NCHW f32) -> FP (b,p,n,c) bf16 ===================================
__global__ __launch_bounds__(256) void k_fp(const float* __restrict__ F,
                                            bf16* __restrict__ FP) {
  int bp = blockIdx.x, b = bp >> 6, p = bp & 63;
  int py = (p >> 3) * 8, px = (p & 7) * 8;
  for (int i = threadIdx.x; i < 64 * 512; i += 256) {
    int n = i >> 9, c = i & 511;
    int y = py + (n >> 3), x = px + (n & 7);
    FP[(size_t)bp * 32768 + i] = f2b(F[((size_t)(b * 512 + c) * 64 + y) * 64 + x]);
  }
}

// ===== softmax(I over n) ; F_l0[b,p,k,c] = bc * sum_n pix[k][n]*Fp[n][c] ===
__global__ __launch_bounds__(256) void k_flocal(const float* __restrict__ I,
        const float* __restrict__ R, const bf16* __restrict__ FP,
        float* __restrict__ FL0) {
  int bp = blockIdx.x, b = bp >> 6, p = bp & 63;
  int tid = threadIdx.x;
  __shared__ float pix[19][64];
  __shared__ float bc[19];
  int py = (p >> 3) * 8, px = (p & 7) * 8;
  for (int i = tid; i < 19 * 64; i += 256) {
    int k = i >> 6, n = i & 63;
    int y = py + (n >> 3), x = px + (n & 7);
    pix[k][n] = I[((size_t)(b * 19 + k) * 64 + y) * 64 + x];
  }
  if (tid < 19) bc[tid] = R[(size_t)(b * 19 + tid) * 64 + p];
  __syncthreads();
  if (tid < 19) {
    float mx = -1e30f;
    for (int n = 0; n < 64; n++) mx = fmaxf(mx, pix[tid][n]);
    float s = 0.f;
    for (int n = 0; n < 64; n++) { float e = __expf(pix[tid][n] - mx); pix[tid][n] = e; s += e; }
    float inv = 1.f / s;
    for (int n = 0; n < 64; n++) pix[tid][n] *= inv;
  }
  __syncthreads();
  for (int i = tid; i < 19 * 512; i += 256) {
    int k = i >> 9, c = i & 511;
    const bf16* fp = FP + (size_t)bp * 32768 + c;
    float s = 0.f;
    for (int n = 0; n < 64; n++) s += pix[k][n] * b2f(fp[n << 9]);
    FL0[((size_t)(b * 64 + p) * 19 + k) * 512 + c] = s * bc[k];
  }
}

// ===== LG part 1: H[b,p,kc] = relu(sum_q w1[p][q]*FL0[b,q,kc] + FL0[b,p,kc])
__global__ __launch_bounds__(256) void k_lg1(const float* __restrict__ FL0,
        const float* __restrict__ w1, float* __restrict__ H) {
  int tid = threadIdx.x;
  int b = blockIdx.y;
  int n0 = blockIdx.x * 256;
  __shared__ float W[64][64];
  __shared__ float Xs[16][256];
  for (int i = tid; i < 4096; i += 256) W[i >> 6][i & 63] = w1[i];
  float acc[64];
  #pragma unroll
  for (int po = 0; po < 64; po++) acc[po] = 0.f;
  for (int q0 = 0; q0 < 64; q0 += 16) {
    __syncthreads();
    for (int i = tid; i < 4096; i += 256) {
      int q = i >> 8, j = i & 255;
      Xs[q][j] = FL0[(size_t)(b * 64 + q0 + q) * 9728 + n0 + j];
    }
    __syncthreads();
    for (int q = 0; q < 16; q++) {
      float xv = Xs[q][tid];
      #pragma unroll
      for (int po = 0; po < 64; po++) acc[po] += W[po][q0 + q] * xv;
    }
  }
  for (int po = 0; po < 64; po++) {
    float r = acc[po] + FL0[(size_t)(b * 64 + po) * 9728 + n0 + tid];
    H[(size_t)(b * 64 + po) * 9728 + n0 + tid] = fmaxf(r, 0.f);
  }
}

// ===== generic GEMM: C[M,N] = A[M,K] @ W[N,K]^T (+bias), W/bias f32 ========
template<bool ABF16, bool BIAS>
__global__ __launch_bounds__(256) void k_gemm_wt(const void* __restrict__ A_,
        const float* __restrict__ W, const float* __restrict__ bias,
        float* __restrict__ C, int Kd, int Nn) {
  int tid = threadIdx.x;
  int m0 = blockIdx.x * 64, n0 = blockIdx.y * 64;
  int tx = tid & 15, ty = tid >> 4;
  __shared__ __align__(16) float As[32][68];
  __shared__ __align__(16) float Bs[32][68];
  float acc[4][4] = {};
  for (int k0 = 0; k0 < Kd; k0 += 32) {
    for (int i = tid; i < 2048; i += 256) {
      int m = i >> 5, kk = i & 31;
      float v;
      if (ABF16) v = b2f(((const bf16*)A_)[(size_t)(m0 + m) * Kd + k0 + kk]);
      else       v = ((const float*)A_)[(size_t)(m0 + m) * Kd + k0 + kk];
      As[kk][m] = v;
    }
    for (int i = tid; i < 2048; i += 256) {
      int n = i >> 5, kk = i & 31;
      Bs[kk][n] = W[(size_t)(n0 + n) * Kd + k0 + kk];
    }
    __syncthreads();
    #pragma unroll
    for (int kk = 0; kk < 32; kk++) {
      float a[4], bv[4];
      *(float4*)a  = *(const float4*)&As[kk][ty * 4];
      *(float4*)bv = *(const float4*)&Bs[kk][tx * 4];
      #pragma unroll
      for (int ii = 0; ii < 4; ii++)
        #pragma unroll
        for (int jj = 0; jj < 4; jj++)
          acc[ii][jj] += a[ii] * bv[jj];
    }
    __syncthreads();
  }
  for (int ii = 0; ii < 4; ii++) {
    int m = m0 + ty * 4 + ii;
    float ov[4];
    #pragma unroll
    for (int jj = 0; jj < 4; jj++) {
      float v = acc[ii][jj];
      if (BIAS) v += bias[n0 + tx * 4 + jj];
      ov[jj] = v;
    }
    *(float4*)&C[(size_t)m * Nn + n0 + tx * 4] = *(float4*)ov;
  }
}

// ===== F_g = sum_p fw[p]*FL + fb ; VAL = F_g @ vw^T + vb ===================
__global__ __launch_bounds__(256) void k_fusev(const float* __restrict__ FL,
        const float* __restrict__ fw, const float* __restrict__ fbv,
        const float* __restrict__ vw, const float* __restrict__ vb,
        float* __restrict__ VAL) {
  int tid = threadIdx.x;
  int bk = blockIdx.x, b = bk / 19, k = bk % 19;
  __shared__ float fwl[64];
  __shared__ float fg[512];
  if (tid < 64) fwl[tid] = fw[tid];
  __syncthreads();
  float fbias = fbv[0];
  for (int c = tid; c < 512; c += 256) {
    float s = 0.f;
    for (int p = 0; p < 64; p++)
      s += fwl[p] * FL[((size_t)(b * 64 + p) * 19 + k) * 512 + c];
    fg[c] = s + fbias;
  }
  __syncthreads();
  int d = tid;
  float s = vb[d];
  for (int c = 0; c < 512; c++) s += fg[c] * vw[(size_t)d * 512 + c];
  VAL[(size_t)bk * 256 + d] = s;
}

// ===== per-patch attention: S=Q K^T, softmax over k, F_s = aff @ V =========
// writes F_s in recovered NHWC layout (b, y, x, d) bf16
__global__ __launch_bounds__(256) void k_attn(const float* __restrict__ Q,
        const float* __restrict__ KEY, const float* __restrict__ VAL,
        bf16* __restrict__ FS) {
  int tid = threadIdx.x;
  int bp = blockIdx.x, b = bp >> 6, p = bp & 63;
  __shared__ float ks[19][256];
  __shared__ float vs[19][256];
  __shared__ float Ss[64][20];
  for (int i = tid; i < 19 * 256; i += 256) {
    ks[i >> 8][i & 255] = KEY[(size_t)bp * 19 * 256 + i];
    vs[i >> 8][i & 255] = VAL[(size_t)b * 19 * 256 + i];
  }
  __syncthreads();
  {
    int n = tid >> 2, kq = tid & 3;
    const float* qrow = Q + ((size_t)bp * 64 + n) * 256;
    for (int k = kq; k < 19; k += 4) {
      float s = 0.f;
      for (int d = 0; d < 256; d++) s += qrow[d] * ks[k][d];
      Ss[n][k] = s;
    }
  }
  __syncthreads();
  if (tid < 64) {
    float mx = -1e30f;
    for (int k = 0; k < 19; k++) mx = fmaxf(mx, Ss[tid][k]);
    float sum = 0.f;
    for (int k = 0; k < 19; k++) { float e = __expf(Ss[tid][k] - mx); Ss[tid][k] = e; sum += e; }
    float inv = 1.f / sum;
    for (int k = 0; k < 19; k++) Ss[tid][k] *= inv;
  }
  __syncthreads();
  {
    int d = tid;
    int py = (p >> 3) * 8, px = (p & 7) * 8;
    for (int nn = 0; nn < 64; nn++) {
      float s = 0.f;
      #pragma unroll
      for (int k = 0; k < 19; k++) s += Ss[nn][k] * vs[k][d];
      int y = py + (nn >> 3), x = px + (nn & 7);
      FS[(((size_t)(b * 64 + y) * 64) + x) * 256 + d] = f2b(s);
    }
  }
}

// ===== conv1x1 256->512 + BN + ReLU + residual F (f32) =====================
__global__ __launch_bounds__(256) void k_conv1(const bf16* __restrict__ FSi,
        const float* __restrict__ w, const float* __restrict__ g,
        const float* __restrict__ bb, const float* __restrict__ F,
        bf16* __restrict__ out) {
  int tid = threadIdx.x;
  int b = blockIdx.x >> 6, y = blockIdx.x & 63;
  int oc0 = blockIdx.y * 64;
  int tx = tid & 15, ty = tid >> 4;
  __shared__ __align__(16) float As[32][68];
  __shared__ __align__(16) float Bs[32][68];
  float acc[4][4] = {};
  for (int c0 = 0; c0 < 256; c0 += 32) {
    for (int i = tid; i < 2048; i += 256) {
      int oc = i >> 5, kk = i & 31;
      As[kk][oc] = w[(size_t)(oc0 + oc) * 256 + c0 + kk];
    }
    for (int i = tid; i < 2048; i += 256) {
      int x = i >> 5, kk = i & 31;
      Bs[kk][x] = b2f(FSi[(((size_t)(b * 64 + y) * 64) + x) * 256 + c0 + kk]);
    }
    __syncthreads();
    #pragma unroll
    for (int kk = 0; kk < 32; kk++) {
      float a[4], bv[4];
      *(float4*)a  = *(const float4*)&As[kk][ty * 4];
      *(float4*)bv = *(const float4*)&Bs[kk][tx * 4];
      #pragma unroll
      for (int ii = 0; ii < 4; ii++)
        #pragma unroll
        for (int jj = 0; jj < 4; jj++)
          acc[ii][jj] += a[ii] * bv[jj];
    }
    __syncthreads();
  }
  #pragma unroll
  for (int ii = 0; ii < 4; ii++) {
    int oc = oc0 + ty * 4 + ii;
    float sc = g[oc] * rsqrtf(1.f + EPSV);
    float bt = bb[oc];
    #pragma unroll
    for (int jj = 0; jj < 4; jj++) {
      int x = tx * 4 + jj;
      float v = fmaxf(acc[ii][jj] * sc + bt, 0.f)
              + F[((size_t)(b * 512 + oc) * 64 + y) * 64 + x];
      out[((size_t)(b * 512 + oc) * 64 + y) * 64 + x] = f2b(v);
    }
  }
}

// ===== conv3x3 (pad 1) over concat(Xa bf16[C1], Xb f32[C2]) + BN + ReLU ====
__global__ __launch_bounds__(256) void k_conv3(const bf16* __restrict__ Xa, int C1,
        const float* __restrict__ Xb, int C2, const bf16* __restrict__ WT,
        const float* __restrict__ g, const float* __restrict__ bb,
        bf16* __restrict__ out) {
  int tid = threadIdx.x;
  int b = blockIdx.x >> 6, y = blockIdx.x & 63;
  int oc0 = blockIdx.y * 64;
  int tx = tid & 15, ty = tid >> 4;
  __shared__ __align__(16) float As[32][68];
  __shared__ __align__(16) float Bs[32][68];
  float acc[4][4] = {};
  int Ct = C1 + C2;
  for (int c0 = 0; c0 < Ct; c0 += 32) {
    bool useA = (c0 < C1);
    int cb = useA ? c0 : (c0 - C1);
    int Cs = useA ? C1 : C2;
    for (int ky = 0; ky < 3; ky++) {
      int yy = y + ky - 1;
      bool yok = (yy >= 0) && (yy < 64);
      for (int kx = 0; kx < 3; kx++) {
        int k9 = ky * 3 + kx;
        for (int i = tid; i < 2048; i += 256) {
          int kk = i >> 6, oc = i & 63;
          As[kk][oc] = b2f(WT[((size_t)k9 * Ct + c0 + kk) * 512 + oc0 + oc]);
        }
        for (int i = tid; i < 2048; i += 256) {
          int kk = i >> 6, x = i & 63;
          int xx = x + kx - 1;
          float v = 0.f;
          if (yok && xx >= 0 && xx < 64) {
            size_t idx = ((size_t)(b * Cs + cb + kk) * 64 + yy) * 64 + xx;
            v = useA ? b2f(Xa[idx]) : Xb[idx];
          }
          Bs[kk][x] = v;
        }
        __syncthreads();
        #pragma unroll
        for (int kk = 0; kk < 32; kk++) {
          float a[4], bv[4];
          *(float4*)a  = *(const float4*)&As[kk][ty * 4];
          *(float4*)bv = *(const float4*)&Bs[kk][tx * 4];
          #pragma unroll
          for (int ii = 0; ii < 4; ii++)
            #pragma unroll
            for (int jj = 0; jj < 4; jj++)
              acc[ii][jj] += a[ii] * bv[jj];
        }
        __syncthreads();
      }
    }
  }
  #pragma unroll
  for (int ii = 0; ii < 4; ii++) {
    int oc = oc0 + ty * 4 + ii;
    float sc = g[oc] * rsqrtf(1.f + EPSV);
    float bt = bb[oc];
    #pragma unroll
    for (int jj = 0; jj < 4; jj++) {
      int x = tx * 4 + jj;
      float v = fmaxf(acc[ii][jj] * sc + bt, 0.f);
      out[((size_t)(b * 512 + oc) * 64 + y) * 64 + x] = f2b(v);
    }
  }
}

// ===== final 1x1: out[b,k,y,x] = sum_ci dw[k,ci]*X3[b,ci,y,x], f32 out =====
__global__ __launch_bounds__(256) void k_final(const bf16* __restrict__ X3,
        const float* __restrict__ dw, float* __restrict__ out) {
  int tid = threadIdx.x;
  int b = blockIdx.x >> 6, y = blockIdx.x & 63;
  __shared__ float W[19 * 512];
  for (int i = tid; i < 19 * 512; i += 256) W[i] = dw[i];
  __syncthreads();
  int x = tid & 63, kg = tid >> 6;
  float acc[5] = {0.f, 0.f, 0.f, 0.f, 0.f};
  for (int ci = 0; ci < 512; ci++) {
    float xv = b2f(X3[((size_t)(b * 512 + ci) * 64 + y) * 64 + x]);
    #pragma unroll
    for (int i = 0; i < 5; i++) {
      int k = kg * 5 + i;
      if (k < 19) acc[i] += xv * W[k * 512 + ci];
    }
  }
  for (int i = 0; i < 5; i++) {
    int k = kg * 5 + i;
    if (k < 19) out[((size_t)(b * 19 + k) * 64 + y) * 64 + x] = acc[i];
  }
}

extern "C" void kernel_launch(void* const* d_in, const int* in_sizes, int n_in,
                              void* d_out, int out_size, void* d_ws, size_t ws_size,
                              hipStream_t stream) {
  (void)in_sizes; (void)n_in; (void)out_size; (void)ws_size;
  const float* M1 = (const float*)d_in[0];
  const float* F  = (const float*)d_in[1];
  const float* Iin= (const float*)d_in[2];
  const float* R  = (const float*)d_in[3];
  const float* w1 = (const float*)d_in[4];
  const float* w2 = (const float*)d_in[5];
  const float* fw = (const float*)d_in[6];
  const float* fb = (const float*)d_in[7];
  const float* qw = (const float*)d_in[8];
  const float* qb = (const float*)d_in[9];
  const float* kw = (const float*)d_in[10];
  const float* kb = (const float*)d_in[11];
  const float* vw = (const float*)d_in[12];
  const float* vb = (const float*)d_in[13];
  const float* c1 = (const float*)d_in[14];
  const float* g1 = (const float*)d_in[15];
  const float* b1 = (const float*)d_in[16];
  const float* c2 = (const float*)d_in[17];
  const float* g2 = (const float*)d_in[18];
  const float* b2 = (const float*)d_in[19];
  const float* c3 = (const float*)d_in[20];
  const float* g3 = (const float*)d_in[21];
  const float* b3 = (const float*)d_in[22];
  const float* dw = (const float*)d_in[23];

  char* ws = (char*)d_ws;
  // workspace layout (bytes). Total 112,013,312 (~107 MB).
  bf16*  FP    = (bf16*) (ws + 0);          // 16,777,216  (B,P,N,C) bf16
  float* QUERY = (float*)(ws + 16777216);   // 16,777,216  (B*P*N, 256) f32
  float* FL0   = (float*)(ws + 33554432);   //  9,961,472  (B,P,K,C) f32 (reused as FL)
  float* H     = (float*)(ws + 43515904);   //  9,961,472
  float* KEY   = (float*)(ws + 53477376);   //  4,980,736
  float* VAL   = (float*)(ws + 58458112);   //     77,824
  bf16*  FS    = (bf16*) (ws + 58535936);   //  8,388,608  NHWC bf16
  bf16*  FO1   = (bf16*) (ws + 66924544);   // 16,777,216  NCHW bf16
  bf16*  WT2   = (bf16*) (ws + 83701760);   //  4,718,592
  bf16*  WT3   = (bf16*) (ws + 88420352);   // 23,592,960
  bf16*  X2    = FP;                        // reuse (FP dead after query GEMM)
  bf16*  X3    = (bf16*)QUERY;              // reuse (QUERY dead after attn)
  float* FL    = FL0;                       // reuse (FL0 dead after LG1)

  k_wt<<<dim3(16, 64),  256, 0, stream>>>(c2, WT2, 512);
  k_wt<<<dim3(16, 320), 256, 0, stream>>>(c3, WT3, 2560);
  k_fp<<<256, 256, 0, stream>>>(F, FP);
  k_flocal<<<256, 256, 0, stream>>>(Iin, R, FP, FL0);
  k_lg1<<<dim3(38, 4), 256, 0, stream>>>(FL0, w1, H);
  k_gemm_wt<false,false><<<dim3(76, 8), 256, 0, stream>>>(H,  w2, nullptr, FL,    512, 512);
  k_fusev<<<76, 256, 0, stream>>>(FL, fw, fb, vw, vb, VAL);
  k_gemm_wt<false,true ><<<dim3(76, 4), 256, 0, stream>>>(FL, kw, kb,      KEY,   512, 256);
  k_gemm_wt<true, true ><<<dim3(256, 4), 256, 0, stream>>>(FP, qw, qb,     QUERY, 512, 256);
  k_attn<<<256, 256, 0, stream>>>(QUERY, KEY, VAL, FS);
  k_conv1<<<dim3(256, 8), 256, 0, stream>>>(FS, c1, g1, b1, F, FO1);
  k_conv3<<<dim3(256, 8), 256, 0, stream>>>(FO1, 512, nullptr, 0,  WT2, g2, b2, X2);
  k_conv3<<<dim3(256, 8), 256, 0, stream>>>(X2,  512, M1, 2048,    WT3, g3, b3, X3);
  k_final<<<256, 256, 0, stream>>>(X3, dw, (float*)d_out);
}

// Round 5
// 6945.679 us; speedup vs baseline: 1.4295x; 1.4295x over previous
//
#include <hip/hip_runtime.h>
#include <hip/hip_bf16.h>

typedef __hip_bfloat16 bf16;
using short8 = __attribute__((ext_vector_type(8))) short;
using f32x4  = __attribute__((ext_vector_type(4))) float;

__device__ __forceinline__ float b2f(bf16 v){ return __bfloat162float(v); }
__device__ __forceinline__ bf16  f2b(float v){ return __float2bfloat16(v); }

#define EPSV 1e-5f

// ===== R2-proven: weight transpose OIHW f32 -> [k9][CI][OC] bf16, OC=512 ===
__global__ __launch_bounds__(256) void k_wt(const float* __restrict__ w,
                                            bf16* __restrict__ wt, int CI) {
  int oc0 = blockIdx.x * 32, ci0 = blockIdx.y * 8;
  for (int i = threadIdx.x; i < 2304; i += 256) {
    int kk = i >> 8, r = i & 255;
    int ci = ci0 + (r >> 5), oc = oc0 + (r & 31);
    wt[((size_t)kk * CI + ci) * 512 + oc] = f2b(w[((size_t)oc * CI + ci) * 9 + kk]);
  }
}

// ===== R2-proven: F (NCHW f32) -> FP (b,p,n,c) bf16 ========================
__global__ __launch_bounds__(256) void k_fp(const float* __restrict__ F,
                                            bf16* __restrict__ FP) {
  int bp = blockIdx.x, b = bp >> 6, p = bp & 63;
  int py = (p >> 3) * 8, px = (p & 7) * 8;
  for (int i = threadIdx.x; i < 64 * 512; i += 256) {
    int n = i >> 9, c = i & 511;
    int y = py + (n >> 3), x = px + (n & 7);
    FP[(size_t)bp * 32768 + i] = f2b(F[((size_t)(b * 512 + c) * 64 + y) * 64 + x]);
  }
}

// ===== R2-proven: softmax(I) ; F_l0 = bc * pix @ Fp ========================
__global__ __launch_bounds__(256) void k_flocal(const float* __restrict__ I,
        const float* __restrict__ R, const bf16* __restrict__ FP,
        float* __restrict__ FL0) {
  int bp = blockIdx.x, b = bp >> 6, p = bp & 63;
  int tid = threadIdx.x;
  __shared__ float pix[19][64];
  __shared__ float bc[19];
  int py = (p >> 3) * 8, px = (p & 7) * 8;
  for (int i = tid; i < 19 * 64; i += 256) {
    int k = i >> 6, n = i & 63;
    int y = py + (n >> 3), x = px + (n & 7);
    pix[k][n] = I[((size_t)(b * 19 + k) * 64 + y) * 64 + x];
  }
  if (tid < 19) bc[tid] = R[(size_t)(b * 19 + tid) * 64 + p];
  __syncthreads();
  if (tid < 19) {
    float mx = -1e30f;
    for (int n = 0; n < 64; n++) mx = fmaxf(mx, pix[tid][n]);
    float s = 0.f;
    for (int n = 0; n < 64; n++) { float e = __expf(pix[tid][n] - mx); pix[tid][n] = e; s += e; }
    float inv = 1.f / s;
    for (int n = 0; n < 64; n++) pix[tid][n] *= inv;
  }
  __syncthreads();
  for (int i = tid; i < 19 * 512; i += 256) {
    int k = i >> 9, c = i & 511;
    const bf16* fp = FP + (size_t)bp * 32768 + c;
    float s = 0.f;
    for (int n = 0; n < 64; n++) s += pix[k][n] * b2f(fp[n << 9]);
    FL0[((size_t)(b * 64 + p) * 19 + k) * 512 + c] = s * bc[k];
  }
}

// ===== R2-proven: LG part 1 ================================================
__global__ __launch_bounds__(256) void k_lg1(const float* __restrict__ FL0,
        const float* __restrict__ w1, float* __restrict__ H) {
  int tid = threadIdx.x;
  int b = blockIdx.y;
  int n0 = blockIdx.x * 256;
  __shared__ float W[64][64];
  __shared__ float Xs[16][256];
  for (int i = tid; i < 4096; i += 256) W[i >> 6][i & 63] = w1[i];
  float acc[64];
  #pragma unroll
  for (int po = 0; po < 64; po++) acc[po] = 0.f;
  for (int q0 = 0; q0 < 64; q0 += 16) {
    __syncthreads();
    for (int i = tid; i < 4096; i += 256) {
      int q = i >> 8, j = i & 255;
      Xs[q][j] = FL0[(size_t)(b * 64 + q0 + q) * 9728 + n0 + j];
    }
    __syncthreads();
    for (int q = 0; q < 16; q++) {
      float xv = Xs[q][tid];
      #pragma unroll
      for (int po = 0; po < 64; po++) acc[po] += W[po][q0 + q] * xv;
    }
  }
  for (int po = 0; po < 64; po++) {
    float r = acc[po] + FL0[(size_t)(b * 64 + po) * 9728 + n0 + tid];
    H[(size_t)(b * 64 + po) * 9728 + n0 + tid] = fmaxf(r, 0.f);
  }
}

// ===== R2-proven: generic GEMM C = A @ W^T (+bias) =========================
template<bool ABF16, bool BIAS>
__global__ __launch_bounds__(256) void k_gemm_wt(const void* __restrict__ A_,
        const float* __restrict__ W, const float* __restrict__ bias,
        float* __restrict__ C, int Kd, int Nn) {
  int tid = threadIdx.x;
  int m0 = blockIdx.x * 64, n0 = blockIdx.y * 64;
  int tx = tid & 15, ty = tid >> 4;
  __shared__ __align__(16) float As[32][68];
  __shared__ __align__(16) float Bs[32][68];
  float acc[4][4] = {};
  for (int k0 = 0; k0 < Kd; k0 += 32) {
    for (int i = tid; i < 2048; i += 256) {
      int m = i >> 5, kk = i & 31;
      float v;
      if (ABF16) v = b2f(((const bf16*)A_)[(size_t)(m0 + m) * Kd + k0 + kk]);
      else       v = ((const float*)A_)[(size_t)(m0 + m) * Kd + k0 + kk];
      As[kk][m] = v;
    }
    for (int i = tid; i < 2048; i += 256) {
      int n = i >> 5, kk = i & 31;
      Bs[kk][n] = W[(size_t)(n0 + n) * Kd + k0 + kk];
    }
    __syncthreads();
    #pragma unroll
    for (int kk = 0; kk < 32; kk++) {
      float a[4], bv[4];
      *(float4*)a  = *(const float4*)&As[kk][ty * 4];
      *(float4*)bv = *(const float4*)&Bs[kk][tx * 4];
      #pragma unroll
      for (int ii = 0; ii < 4; ii++)
        #pragma unroll
        for (int jj = 0; jj < 4; jj++)
          acc[ii][jj] += a[ii] * bv[jj];
    }
    __syncthreads();
  }
  for (int ii = 0; ii < 4; ii++) {
    int m = m0 + ty * 4 + ii;
    float ov[4];
    #pragma unroll
    for (int jj = 0; jj < 4; jj++) {
      float v = acc[ii][jj];
      if (BIAS) v += bias[n0 + tx * 4 + jj];
      ov[jj] = v;
    }
    *(float4*)&C[(size_t)m * Nn + n0 + tx * 4] = *(float4*)ov;
  }
}

// ===== R2-proven: fuse + value =============================================
__global__ __launch_bounds__(256) void k_fusev(const float* __restrict__ FL,
        const float* __restrict__ fw, const float* __restrict__ fbv,
        const float* __restrict__ vw, const float* __restrict__ vb,
        float* __restrict__ VAL) {
  int tid = threadIdx.x;
  int bk = blockIdx.x, b = bk / 19, k = bk % 19;
  __shared__ float fwl[64];
  __shared__ float fg[512];
  if (tid < 64) fwl[tid] = fw[tid];
  __syncthreads();
  float fbias = fbv[0];
  for (int c = tid; c < 512; c += 256) {
    float s = 0.f;
    for (int p = 0; p < 64; p++)
      s += fwl[p] * FL[((size_t)(b * 64 + p) * 19 + k) * 512 + c];
    fg[c] = s + fbias;
  }
  __syncthreads();
  int d = tid;
  float s = vb[d];
  for (int c = 0; c < 512; c++) s += fg[c] * vw[(size_t)d * 512 + c];
  VAL[(size_t)bk * 256 + d] = s;
}

// ===== R2-proven: per-patch attention -> FS NHWC bf16 (C=256) ==============
__global__ __launch_bounds__(256) void k_attn(const float* __restrict__ Q,
        const float* __restrict__ KEY, const float* __restrict__ VAL,
        bf16* __restrict__ FS) {
  int tid = threadIdx.x;
  int bp = blockIdx.x, b = bp >> 6, p = bp & 63;
  __shared__ float ks[19][256];
  __shared__ float vs[19][256];
  __shared__ float Ss[64][20];
  for (int i = tid; i < 19 * 256; i += 256) {
    ks[i >> 8][i & 255] = KEY[(size_t)bp * 19 * 256 + i];
    vs[i >> 8][i & 255] = VAL[(size_t)b * 19 * 256 + i];
  }
  __syncthreads();
  {
    int n = tid >> 2, kq = tid & 3;
    const float* qrow = Q + ((size_t)bp * 64 + n) * 256;
    for (int k = kq; k < 19; k += 4) {
      float s = 0.f;
      for (int d = 0; d < 256; d++) s += qrow[d] * ks[k][d];
      Ss[n][k] = s;
    }
  }
  __syncthreads();
  if (tid < 64) {
    float mx = -1e30f;
    for (int k = 0; k < 19; k++) mx = fmaxf(mx, Ss[tid][k]);
    float sum = 0.f;
    for (int k = 0; k < 19; k++) { float e = __expf(Ss[tid][k] - mx); Ss[tid][k] = e; sum += e; }
    float inv = 1.f / sum;
    for (int k = 0; k < 19; k++) Ss[tid][k] *= inv;
  }
  __syncthreads();
  {
    int d = tid;
    int py = (p >> 3) * 8, px = (p & 7) * 8;
    for (int nn = 0; nn < 64; nn++) {
      float s = 0.f;
      #pragma unroll
      for (int k = 0; k < 19; k++) s += Ss[nn][k] * vs[k][d];
      int y = py + (nn >> 3), x = px + (nn & 7);
      FS[(((size_t)(b * 64 + y) * 64) + x) * 256 + d] = f2b(s);
    }
  }
}

// ===== R2-proven: fp32 conv1x1 256->512 + BN + ReLU + residual F ===========
__global__ __launch_bounds__(256) void k_conv1(const bf16* __restrict__ FSi,
        const float* __restrict__ w, const float* __restrict__ g,
        const float* __restrict__ bb, const float* __restrict__ F,
        bf16* __restrict__ out) {
  int tid = threadIdx.x;
  int b = blockIdx.x >> 6, y = blockIdx.x & 63;
  int oc0 = blockIdx.y * 64;
  int tx = tid & 15, ty = tid >> 4;
  __shared__ __align__(16) float As[32][68];
  __shared__ __align__(16) float Bs[32][68];
  float acc[4][4] = {};
  for (int c0 = 0; c0 < 256; c0 += 32) {
    for (int i = tid; i < 2048; i += 256) {
      int oc = i >> 5, kk = i & 31;
      As[kk][oc] = w[(size_t)(oc0 + oc) * 256 + c0 + kk];
    }
    for (int i = tid; i < 2048; i += 256) {
      int x = i >> 5, kk = i & 31;
      Bs[kk][x] = b2f(FSi[(((size_t)(b * 64 + y) * 64) + x) * 256 + c0 + kk]);
    }
    __syncthreads();
    #pragma unroll
    for (int kk = 0; kk < 32; kk++) {
      float a[4], bv[4];
      *(float4*)a  = *(const float4*)&As[kk][ty * 4];
      *(float4*)bv = *(const float4*)&Bs[kk][tx * 4];
      #pragma unroll
      for (int ii = 0; ii < 4; ii++)
        #pragma unroll
        for (int jj = 0; jj < 4; jj++)
          acc[ii][jj] += a[ii] * bv[jj];
    }
    __syncthreads();
  }
  #pragma unroll
  for (int ii = 0; ii < 4; ii++) {
    int oc = oc0 + ty * 4 + ii;
    float sc = g[oc] * rsqrtf(1.f + EPSV);
    float bt = bb[oc];
    #pragma unroll
    for (int jj = 0; jj < 4; jj++) {
      int x = tx * 4 + jj;
      float v = fmaxf(acc[ii][jj] * sc + bt, 0.f)
              + F[((size_t)(b * 512 + oc) * 64 + y) * 64 + x];
      out[((size_t)(b * 512 + oc) * 64 + y) * 64 + x] = f2b(v);
    }
  }
}

// ===== NEW (only change vs R2): MFMA conv3x3 pad1, concat(Xa bf16, Xb f32) =
// Same grid/staging index math as R2's k_conv3; inner product -> MFMA.
// LDS layout [q][row][8] so A/B fragments are contiguous 16B loads.
// wave w: 32oc x 32x quadrant; 2x2 tiles of 16x16x32.
__global__ __launch_bounds__(256) void k_conv3m(const bf16* __restrict__ Xa, int C1,
        const float* __restrict__ Xb, int C2, const bf16* __restrict__ WT,
        const float* __restrict__ g, const float* __restrict__ bb,
        bf16* __restrict__ out) {
  int tid = threadIdx.x;
  int b = blockIdx.x >> 6, y = blockIdx.x & 63;
  int oc0 = blockIdx.y * 64;
  int w = tid >> 6, lane = tid & 63;
  int qd = lane >> 4, ln = lane & 15;
  int woc = (w & 1) * 32, wx = (w >> 1) * 32;
  __shared__ alignas(16) bf16 Aw[4][64][8];   // [q][oc][j] = W[oc][k=q*8+j]
  __shared__ alignas(16) bf16 Bx[4][64][8];   // [q][x][j]  = X[x][k=q*8+j]
  f32x4 acc[2][2];
  #pragma unroll
  for (int i = 0; i < 2; i++)
    #pragma unroll
    for (int j = 0; j < 2; j++) acc[i][j] = (f32x4){0.f, 0.f, 0.f, 0.f};
  int Ct = C1 + C2;
  for (int c0 = 0; c0 < Ct; c0 += 32) {
    bool useA = (c0 < C1);
    int cb = useA ? c0 : (c0 - C1);
    int Cs = useA ? C1 : C2;
    for (int ky = 0; ky < 3; ky++) {
      int yy = y + ky - 1;
      bool yok = (unsigned)yy < 64u;
      for (int kx = 0; kx < 3; kx++) {
        int k9 = ky * 3 + kx;
        __syncthreads();
        for (int i = tid; i < 2048; i += 256) {
          int kk = i >> 6, oc = i & 63;
          Aw[kk >> 3][oc][kk & 7] =
              WT[((size_t)k9 * Ct + c0 + kk) * 512 + oc0 + oc];
        }
        for (int i = tid; i < 2048; i += 256) {
          int kk = i >> 6, x = i & 63;
          int xx = x + kx - 1;
          bf16 v = f2b(0.f);
          if (yok && (unsigned)xx < 64u) {
            size_t idx = ((size_t)(b * Cs + cb + kk) * 64 + yy) * 64 + xx;
            v = useA ? Xa[idx] : f2b(Xb[idx]);
          }
          Bx[kk >> 3][x][kk & 7] = v;
        }
        __syncthreads();
        short8 af[2], bfr[2];
        #pragma unroll
        for (int mi = 0; mi < 2; mi++)
          af[mi] = *(const short8*)&Aw[qd][woc + mi * 16 + ln][0];
        #pragma unroll
        for (int ni = 0; ni < 2; ni++)
          bfr[ni] = *(const short8*)&Bx[qd][wx + ni * 16 + ln][0];
        #pragma unroll
        for (int mi = 0; mi < 2; mi++)
          #pragma unroll
          for (int ni = 0; ni < 2; ni++)
            acc[mi][ni] = __builtin_amdgcn_mfma_f32_16x16x32_bf16(
                af[mi], bfr[ni], acc[mi][ni], 0, 0, 0);
      }
    }
  }
  // epilogue: D[m][n] lane map col=lane&15, row=quad*4+reg
  #pragma unroll
  for (int mi = 0; mi < 2; mi++) {
    int ocb = oc0 + woc + mi * 16 + qd * 4;
    #pragma unroll
    for (int r = 0; r < 4; r++) {
      int oc = ocb + r;
      float sc = g[oc] * rsqrtf(1.f + EPSV);
      float bt = bb[oc];
      #pragma unroll
      for (int ni = 0; ni < 2; ni++) {
        int x = wx + ni * 16 + ln;
        float v = fmaxf(acc[mi][ni][r] * sc + bt, 0.f);
        out[((size_t)(b * 512 + oc) * 64 + y) * 64 + x] = f2b(v);
      }
    }
  }
}

// ===== R2-proven: final 1x1 from NCHW ======================================
__global__ __launch_bounds__(256) void k_final(const bf16* __restrict__ X3,
        const float* __restrict__ dw, float* __restrict__ out) {
  int tid = threadIdx.x;
  int b = blockIdx.x >> 6, y = blockIdx.x & 63;
  __shared__ float W[19 * 512];
  for (int i = tid; i < 19 * 512; i += 256) W[i] = dw[i];
  __syncthreads();
  int x = tid & 63, kg = tid >> 6;
  float acc[5] = {0.f, 0.f, 0.f, 0.f, 0.f};
  for (int ci = 0; ci < 512; ci++) {
    float xv = b2f(X3[((size_t)(b * 512 + ci) * 64 + y) * 64 + x]);
    #pragma unroll
    for (int i = 0; i < 5; i++) {
      int k = kg * 5 + i;
      if (k < 19) acc[i] += xv * W[k * 512 + ci];
    }
  }
  for (int i = 0; i < 5; i++) {
    int k = kg * 5 + i;
    if (k < 19) out[((size_t)(b * 19 + k) * 64 + y) * 64 + x] = acc[i];
  }
}

extern "C" void kernel_launch(void* const* d_in, const int* in_sizes, int n_in,
                              void* d_out, int out_size, void* d_ws, size_t ws_size,
                              hipStream_t stream) {
  (void)in_sizes; (void)n_in; (void)out_size; (void)ws_size;
  const float* M1 = (const float*)d_in[0];
  const float* F  = (const float*)d_in[1];
  const float* Iin= (const float*)d_in[2];
  const float* R  = (const float*)d_in[3];
  const float* w1 = (const float*)d_in[4];
  const float* w2 = (const float*)d_in[5];
  const float* fw = (const float*)d_in[6];
  const float* fb = (const float*)d_in[7];
  const float* qw = (const float*)d_in[8];
  const float* qb = (const float*)d_in[9];
  const float* kw = (const float*)d_in[10];
  const float* kb = (const float*)d_in[11];
  const float* vw = (const float*)d_in[12];
  const float* vb = (const float*)d_in[13];
  const float* c1 = (const float*)d_in[14];
  const float* g1 = (const float*)d_in[15];
  const float* b1 = (const float*)d_in[16];
  const float* c2 = (const float*)d_in[17];
  const float* g2 = (const float*)d_in[18];
  const float* b2 = (const float*)d_in[19];
  const float* c3 = (const float*)d_in[20];
  const float* g3 = (const float*)d_in[21];
  const float* b3 = (const float*)d_in[22];
  const float* dw = (const float*)d_in[23];

  char* ws = (char*)d_ws;
  // R2-proven workspace layout (bytes). Total 112,013,312 (~107 MB).
  bf16*  FP    = (bf16*) (ws + 0);          // 16,777,216  (B,P,N,C) bf16
  float* QUERY = (float*)(ws + 16777216);   // 16,777,216  f32
  float* FL0   = (float*)(ws + 33554432);   //  9,961,472  f32
  float* H     = (float*)(ws + 43515904);   //  9,961,472
  float* KEY   = (float*)(ws + 53477376);   //  4,980,736
  float* VAL   = (float*)(ws + 58458112);   //     77,824
  bf16*  FS    = (bf16*) (ws + 58535936);   //  8,388,608  NHWC bf16 (C=256)
  bf16*  FO1   = (bf16*) (ws + 66924544);   // 16,777,216  NCHW bf16
  bf16*  WT2   = (bf16*) (ws + 83701760);   //  4,718,592
  bf16*  WT3   = (bf16*) (ws + 88420352);   // 23,592,960
  bf16*  X2    = FP;                        // overlay, 16.7 MB (FP dead after query GEMM)
  bf16*  X3    = (bf16*)QUERY;              // overlay, 16.7 MB (QUERY dead after attn)
  float* FL    = FL0;                       // overlay (FL0 dead after lg1)

  k_wt<<<dim3(16, 64),  256, 0, stream>>>(c2, WT2, 512);
  k_wt<<<dim3(16, 320), 256, 0, stream>>>(c3, WT3, 2560);
  k_fp<<<256, 256, 0, stream>>>(F, FP);
  k_flocal<<<256, 256, 0, stream>>>(Iin, R, FP, FL0);
  k_lg1<<<dim3(38, 4), 256, 0, stream>>>(FL0, w1, H);
  k_gemm_wt<false,false><<<dim3(76, 8), 256, 0, stream>>>(H,  w2, nullptr, FL,    512, 512);
  k_fusev<<<76, 256, 0, stream>>>(FL, fw, fb, vw, vb, VAL);
  k_gemm_wt<false,true ><<<dim3(76, 4), 256, 0, stream>>>(FL, kw, kb,      KEY,   512, 256);
  k_gemm_wt<true, true ><<<dim3(256, 4), 256, 0, stream>>>(FP, qw, qb,     QUERY, 512, 256);
  k_attn<<<256, 256, 0, stream>>>(QUERY, KEY, VAL, FS);
  k_conv1<<<dim3(256, 8), 256, 0, stream>>>(FS, c1, g1, b1, F, FO1);
  k_conv3m<<<dim3(256, 8), 256, 0, stream>>>(FO1, 512, (const float*)nullptr, 0,
                                             WT2, g2, b2, X2);
  k_conv3m<<<dim3(256, 8), 256, 0, stream>>>(X2,  512, M1, 2048,
                                             WT3, g3, b3, X3);
  k_final<<<256, 256, 0, stream>>>(X3, dw, (float*)d_out);
}